// Round 4
// baseline (302.704 us; speedup 1.0000x reference)
//
#include <hip/hip_runtime.h>
#include <hip/hip_bf16.h>

#define B_ 1024
#define L_ 256
#define D_ 256
#define H_ 512
#define U_ 512
#define M_ (B_ * L_)   // 262144 rows of the big GEMM

#define BM 128
#define BN 128
#define BK 64

typedef float f32x4 __attribute__((ext_vector_type(4)));
typedef short bf16x8 __attribute__((ext_vector_type(8)));  // 8 bf16 in 4 VGPRs

__device__ __forceinline__ short f2bf(float f) {
  // round-to-nearest-even fp32 -> bf16 (inputs are finite, no NaN handling)
  unsigned u = __float_as_uint(f);
  u += 0x7fffu + ((u >> 16) & 1u);
  return (short)(u >> 16);
}

__device__ __forceinline__ void load16_g2l(const void* g, void* l) {
  // async global->LDS, 16B per lane; LDS dest must be uniform-base + lane*16
  __builtin_amdgcn_global_load_lds(
      (const __attribute__((address_space(1))) unsigned int*)g,
      (__attribute__((address_space(3))) unsigned int*)l, 16, 0, 0);
}

__device__ __forceinline__ float fast_tanh(float x) {
  float e = __expf(2.0f * x);               // v_exp_f32 based, ~1ulp
  return 1.0f - 2.0f * __builtin_amdgcn_rcpf(e + 1.0f);
}

// ---------------- prep: W1 [D,U] fp32 -> W1T [U,D] bf16 ----------------
__global__ void k_w1t(const float* __restrict__ W1, short* __restrict__ W1T) {
  int idx = blockIdx.x * 256 + threadIdx.x;   // over U_*D_ = 131072
  int u = idx >> 8;      // / D_
  int d = idx & 255;
  W1T[idx] = f2bf(W1[(size_t)d * U_ + u]);
}

// ---------------- projh[b,u] = hidden[b,:] @ W2[:,u] + b1[u] + b2[u] ----------------
__global__ void k_projh(const float* __restrict__ hidden, const float* __restrict__ W2,
                        const float* __restrict__ b1, const float* __restrict__ b2,
                        float* __restrict__ ph) {
  int u = blockIdx.x * 256 + threadIdx.x;
  int b0 = blockIdx.y * 8;
  float acc[8] = {0.f, 0.f, 0.f, 0.f, 0.f, 0.f, 0.f, 0.f};
  for (int h = 0; h < H_; ++h) {
    float w = W2[(size_t)h * U_ + u];
#pragma unroll
    for (int i = 0; i < 8; ++i) acc[i] = fmaf(hidden[(size_t)(b0 + i) * H_ + h], w, acc[i]);
  }
  float bias = b1[u] + b2[u];
#pragma unroll
  for (int i = 0; i < 8; ++i) ph[(size_t)(b0 + i) * U_ + u] = acc[i] + bias;
}

// ---------------- main: logits partials via bf16 MFMA + tanh + Wv reduce ----------------
// grid 8192: bid&3 = ntile (4), bid>>2 = mtile (2048). 256 threads = 4 waves (2x2 of 64x64).
__global__ __launch_bounds__(256, 2) void k_gemm(
    const float* __restrict__ F,    // [M_, D_] fp32 features
    const short* __restrict__ W1T,  // [U_, D_] bf16
    const float* __restrict__ ph,   // [B_, U_]
    const float* __restrict__ Wv,   // [U_]
    float* __restrict__ logits) {   // [M_], pre-zeroed
  __shared__ __align__(16) float As[BM * BK];   // 32 KB, fp32, swizzled 16B slots
  __shared__ __align__(16) short Bs[BN * BK];   // 16 KB, bf16 [n][k], swizzled

  const int tid = threadIdx.x;
  const int lane = tid & 63;
  const int wid = tid >> 6;
  const int wr = wid >> 1, wc = wid & 1;
  const int ntile = blockIdx.x & 3;
  const int mtile = blockIdx.x >> 2;
  const int m0 = mtile * BM;
  const int n0 = ntile * BN;
  const int b = m0 >> 8;   // 128-row tile lies within one batch (128 | 256)

  const f32x4* As4 = (const f32x4*)As;
  const bf16x8* Bs8 = (const bf16x8*)Bs;

  f32x4 acc[4][4];
  const f32x4 fz = {0.f, 0.f, 0.f, 0.f};
#pragma unroll
  for (int mi = 0; mi < 4; ++mi)
#pragma unroll
    for (int ni = 0; ni < 4; ++ni) acc[mi][ni] = fz;

  for (int kt = 0; kt < 4; ++kt) {
    if (kt) __syncthreads();
    // stage A: 128 rows x 64 k fp32 = 2048 16B-slots; slot s holds global kq = (s&15)^(row&7)
#pragma unroll
    for (int i = 0; i < 8; ++i) {
      int s = i * 256 + tid;
      int row = s >> 4;
      int kq = (s & 15) ^ (row & 7);
      load16_g2l(F + (size_t)(m0 + row) * D_ + (kt * BK + kq * 4), &As[s * 4]);
    }
    // stage B: 128 n x 64 k bf16 = 1024 16B-slots; slot s holds global kq = (s&7)^(n&7)
#pragma unroll
    for (int i = 0; i < 4; ++i) {
      int s = i * 256 + tid;
      int n = s >> 3;
      int kq = (s & 7) ^ (n & 7);
      load16_g2l(W1T + (size_t)(n0 + n) * D_ + (kt * BK + kq * 8), &Bs[s * 8]);
    }
    __syncthreads();  // compiler drains vmcnt before barrier

#pragma unroll
    for (int kk = 0; kk < 2; ++kk) {
      bf16x8 af[4], bfr[4];
#pragma unroll
      for (int mi = 0; mi < 4; ++mi) {
        int rA = wr * 64 + mi * 16 + (lane & 15);
        int kq0 = kk * 8 + ((lane >> 4) << 1);   // 4-float units
        f32x4 f0 = As4[rA * 16 + (kq0 ^ (rA & 7))];
        f32x4 f1 = As4[rA * 16 + ((kq0 + 1) ^ (rA & 7))];
        bf16x8 a;
        a[0] = f2bf(f0[0]); a[1] = f2bf(f0[1]); a[2] = f2bf(f0[2]); a[3] = f2bf(f0[3]);
        a[4] = f2bf(f1[0]); a[5] = f2bf(f1[1]); a[6] = f2bf(f1[2]); a[7] = f2bf(f1[3]);
        af[mi] = a;
      }
#pragma unroll
      for (int ni = 0; ni < 4; ++ni) {
        int nB = wc * 64 + ni * 16 + (lane & 15);
        int kqb = kk * 4 + (lane >> 4);          // 8-bf16 units
        bfr[ni] = Bs8[nB * 8 + (kqb ^ (nB & 7))];
      }
#pragma unroll
      for (int mi = 0; mi < 4; ++mi)
#pragma unroll
        for (int ni = 0; ni < 4; ++ni)
          acc[mi][ni] = __builtin_amdgcn_mfma_f32_16x16x32_bf16(af[mi], bfr[ni], acc[mi][ni], 0, 0, 0);
    }
  }

  // epilogue: x = acc + ph[b,u]; t = tanh(x); partial logit = sum_u t*Wv[u]
  const float* phr = ph + (size_t)b * U_;
  float phv[4], wvv[4];
#pragma unroll
  for (int ni = 0; ni < 4; ++ni) {
    int u = n0 + wc * 64 + ni * 16 + (lane & 15);
    phv[ni] = phr[u];
    wvv[ni] = Wv[u];
  }
#pragma unroll
  for (int mi = 0; mi < 4; ++mi) {
    float cs[4] = {0.f, 0.f, 0.f, 0.f};
#pragma unroll
    for (int ni = 0; ni < 4; ++ni) {
#pragma unroll
      for (int r = 0; r < 4; ++r) {
        float x = acc[mi][ni][r] + phv[ni];
        cs[r] += fast_tanh(x) * wvv[ni];
      }
    }
    // reduce across the 16 column-lanes (C layout: col = lane&15, row = (lane>>4)*4+r)
#pragma unroll
    for (int off = 1; off < 16; off <<= 1) {
#pragma unroll
      for (int r = 0; r < 4; ++r) cs[r] += __shfl_xor(cs[r], off);
    }
    if ((lane & 15) == 0) {
      int g = m0 + wr * 64 + mi * 16 + ((lane >> 4) << 2);
#pragma unroll
      for (int r = 0; r < 4; ++r) atomicAdd(&logits[g + r], cs[r]);
    }
  }
}

// ---------------- softmax over L per batch (bv is shift-invariant, dropped) ----------------
__global__ void k_softmax(const float* __restrict__ logits, float* __restrict__ outw) {
  __shared__ float red[8];
  int b = blockIdx.x, t = threadIdx.x;
  float x = logits[(size_t)b * L_ + t];
  float m = x;
#pragma unroll
  for (int off = 32; off >= 1; off >>= 1) m = fmaxf(m, __shfl_xor(m, off));
  if ((t & 63) == 0) red[t >> 6] = m;
  __syncthreads();
  m = fmaxf(fmaxf(red[0], red[1]), fmaxf(red[2], red[3]));
  float e = __expf(x - m);
  float s = e;
#pragma unroll
  for (int off = 32; off >= 1; off >>= 1) s += __shfl_xor(s, off);
  if ((t & 63) == 0) red[4 + (t >> 6)] = s;
  __syncthreads();
  s = (red[4] + red[5]) + (red[6] + red[7]);
  outw[(size_t)b * L_ + t] = e / s;
}

// ---------------- context[b,d] = sum_l w[b,l] * features[b,l,d] (fp32) ----------------
__global__ void k_ctx(const float* __restrict__ F, const float* __restrict__ w,
                      float* __restrict__ ctx) {
  __shared__ float wl[L_];
  __shared__ f32x4 part[256];
  int b = blockIdx.x, t = threadIdx.x;
  wl[t] = w[(size_t)b * L_ + t];
  __syncthreads();
  int lq = t >> 6, dq = t & 63;
  const f32x4* F4 = (const f32x4*)(F + (size_t)b * L_ * D_);
  f32x4 acc = {0.f, 0.f, 0.f, 0.f};
  for (int l = lq; l < L_; l += 4) acc += wl[l] * F4[l * 64 + dq];
  part[t] = acc;
  __syncthreads();
  if (lq == 0) {
    f32x4 r = (part[t] + part[t + 64]) + (part[t + 128] + part[t + 192]);
    ((f32x4*)ctx)[(size_t)b * 64 + dq] = r;
  }
}

extern "C" void kernel_launch(void* const* d_in, const int* in_sizes, int n_in,
                              void* d_out, int out_size, void* d_ws, size_t ws_size,
                              hipStream_t stream) {
  const float* F      = (const float*)d_in[0];  // [B,L,D]
  const float* hidden = (const float*)d_in[1];  // [B,H]
  const float* W1     = (const float*)d_in[2];  // [D,U]
  const float* b1     = (const float*)d_in[3];  // [U]
  const float* W2     = (const float*)d_in[4];  // [H,U]
  const float* b2     = (const float*)d_in[5];  // [U]
  const float* Wv     = (const float*)d_in[6];  // [U,1]
  // d_in[7] = bv: shift-invariant under softmax, unused

  float* out_ctx = (float*)d_out;                        // [B,D] = 262144 floats
  float* out_w   = out_ctx + (size_t)B_ * D_;            // [B,L,1] = 262144 floats

  char* ws = (char*)d_ws;
  short* W1T   = (short*)ws;                             // 256 KB bf16 [U,D]
  float* ph    = (float*)(ws + 262144);                  // 2 MB fp32 [B,U]
  float* logits = (float*)(ws + 262144 + 2097152);       // 1 MB fp32 [B*L]

  hipMemsetAsync(logits, 0, (size_t)M_ * sizeof(float), stream);
  k_w1t<<<512, 256, 0, stream>>>(W1, W1T);
  k_projh<<<dim3(2, 128), 256, 0, stream>>>(hidden, W2, b1, b2, ph);
  k_gemm<<<8192, 256, 0, stream>>>(F, W1T, ph, Wv, logits);
  k_softmax<<<1024, 256, 0, stream>>>(logits, out_w);
  k_ctx<<<1024, 256, 0, stream>>>(F, out_w, out_ctx);
}

// Round 6
// 240.522 us; speedup vs baseline: 1.2585x; 1.2585x over previous
//
#include <hip/hip_runtime.h>
#include <hip/hip_bf16.h>

#define B_ 1024
#define L_ 256
#define D_ 256
#define H_ 512
#define U_ 512
#define M_ (B_ * L_)   // 262144 rows of the big GEMM

#define BM 128
#define BN 128
#define BK 64

typedef float f32x4 __attribute__((ext_vector_type(4)));
typedef short bf16x8 __attribute__((ext_vector_type(8)));  // 8 bf16 in 4 VGPRs

__device__ __forceinline__ short f2bf(float f) {
  // round-to-nearest-even fp32 -> bf16 (inputs are finite, no NaN handling)
  unsigned u = __float_as_uint(f);
  u += 0x7fffu + ((u >> 16) & 1u);
  return (short)(u >> 16);
}

__device__ __forceinline__ void load16_g2l(const void* g, void* l) {
  // async global->LDS, 16B per lane; LDS dest must be uniform-base + lane*16
  __builtin_amdgcn_global_load_lds(
      (const __attribute__((address_space(1))) unsigned int*)g,
      (__attribute__((address_space(3))) unsigned int*)l, 16, 0, 0);
}

__device__ __forceinline__ float fast_tanh(float x) {
  float e = __expf(2.0f * x);               // v_exp_f32 based, ~1ulp
  return 1.0f - 2.0f * __builtin_amdgcn_rcpf(e + 1.0f);
}

// ---------------- prep: W1 [D,U] fp32 -> W1T [U,D] bf16 ----------------
__global__ void k_w1t(const float* __restrict__ W1, short* __restrict__ W1T) {
  int idx = blockIdx.x * 256 + threadIdx.x;   // over U_*D_ = 131072
  int u = idx >> 8;      // / D_
  int d = idx & 255;
  W1T[idx] = f2bf(W1[(size_t)d * U_ + u]);
}

// ---------------- projh[b,u] = hidden[b,:] @ W2[:,u] + b1[u] + b2[u] ----------------
__global__ void k_projh(const float* __restrict__ hidden, const float* __restrict__ W2,
                        const float* __restrict__ b1, const float* __restrict__ b2,
                        float* __restrict__ ph) {
  int u = blockIdx.x * 256 + threadIdx.x;
  int b0 = blockIdx.y * 8;
  float acc[8] = {0.f, 0.f, 0.f, 0.f, 0.f, 0.f, 0.f, 0.f};
  for (int h = 0; h < H_; ++h) {
    float w = W2[(size_t)h * U_ + u];
#pragma unroll
    for (int i = 0; i < 8; ++i) acc[i] = fmaf(hidden[(size_t)(b0 + i) * H_ + h], w, acc[i]);
  }
  float bias = b1[u] + b2[u];
#pragma unroll
  for (int i = 0; i < 8; ++i) ph[(size_t)(b0 + i) * U_ + u] = acc[i] + bias;
}

// ---------------- main: logits partials via bf16 MFMA + tanh + Wv reduce ----------------
// grid 8192, XCD-chunked swizzle (8192%8==0 -> bijective). 256 threads = 4 waves (2x2 of 64x64).
// A (features) reg-staged with one fp32->bf16 cast per element per block; B via global_load_lds.
__global__ __launch_bounds__(256, 3) void k_gemm(
    const float* __restrict__ F,    // [M_, D_] fp32 features
    const short* __restrict__ W1T,  // [U_, D_] bf16
    const float* __restrict__ ph,   // [B_, U_]
    const float* __restrict__ Wv,   // [U_]
    float* __restrict__ logits) {   // [M_], pre-zeroed
  __shared__ __align__(16) short As[BM * BK];   // 16 KB bf16 [row][k], swizzled 16B slots
  __shared__ __align__(16) short Bs[BN * BK];   // 16 KB bf16 [n][k],   swizzled 16B slots

  const int tid = threadIdx.x;
  const int lane = tid & 63;
  const int hi = lane >> 4;
  const int wid = tid >> 6;
  const int wr = wid >> 1, wc = wid & 1;
  // XCD swizzle: XCD x = blockIdx%8 owns contiguous tile chunk -> the 4 ntile
  // blocks sharing an A-tile run on the SAME XCD's L2.
  const int tile = ((blockIdx.x & 7) << 10) | (blockIdx.x >> 3);
  const int ntile = tile & 3;
  const int mtile = tile >> 2;
  const int m0 = mtile * BM;
  const int n0 = ntile * BN;
  const int b = m0 >> 8;   // 128-row tile lies within one batch (128 | 256)

  const bf16x8* As8 = (const bf16x8*)As;
  const bf16x8* Bs8 = (const bf16x8*)Bs;

  // ---- precompute staging addresses (row/kq fixed per thread, advance by BK per kt) ----
  // A: 1024 slots (128 rows x 8 slots of 8 bf16). slot s holds global chunk kq = (s&7)^(row&7).
  const float* agp[4];
  int aslot[4];
  // B: 1024 slots (128 n x 8 slots). slot s holds global chunk kq = (s&7)^(n&7).
  const short* bgp[4];
#pragma unroll
  for (int i = 0; i < 4; ++i) {
    int s = i * 256 + tid;
    int arow = s >> 3;
    int akq = (s & 7) ^ (arow & 7);
    agp[i] = F + (size_t)(m0 + arow) * D_ + akq * 8;
    aslot[i] = s;
    bgp[i] = W1T + (size_t)(n0 + arow) * D_ + akq * 8;  // same (row,slot) decomposition
  }

  f32x4 acc[4][4];
  const f32x4 fz = {0.f, 0.f, 0.f, 0.f};
#pragma unroll
  for (int mi = 0; mi < 4; ++mi)
#pragma unroll
    for (int ni = 0; ni < 4; ++ni) acc[mi][ni] = fz;

  for (int kt = 0; kt < 4; ++kt) {
    // issue A global loads early (overlaps prior compute / the barrier)
    f32x4 ar[4][2];
#pragma unroll
    for (int i = 0; i < 4; ++i) {
      ar[i][0] = *(const f32x4*)(agp[i]);
      ar[i][1] = *(const f32x4*)(agp[i] + 4);
      agp[i] += BK;
    }
    if (kt) __syncthreads();   // previous tile fully consumed before overwrite
    // B: async global->LDS (16B/lane)
#pragma unroll
    for (int i = 0; i < 4; ++i) {
      load16_g2l(bgp[i], &Bs[(size_t)(i * 256 + tid) * 8]);
      bgp[i] += BK;
    }
    // A: cast once, vector LDS write (swizzled slot = linear s; source was pre-swizzled)
#pragma unroll
    for (int i = 0; i < 4; ++i) {
      bf16x8 w;
#pragma unroll
      for (int j = 0; j < 4; ++j) { w[j] = f2bf(ar[i][0][j]); w[4 + j] = f2bf(ar[i][1][j]); }
      ((bf16x8*)As)[aslot[i]] = w;
    }
    __syncthreads();           // drains vmcnt (B g2l) + lgkmcnt (A writes)

#pragma unroll
    for (int kk = 0; kk < 2; ++kk) {
      bf16x8 af[4], bfr[4];
#pragma unroll
      for (int mi = 0; mi < 4; ++mi) {
        int rA = wr * 64 + mi * 16 + (lane & 15);
        af[mi] = As8[rA * 8 + ((kk * 4 + hi) ^ (rA & 7))];
      }
#pragma unroll
      for (int ni = 0; ni < 4; ++ni) {
        int nB = wc * 64 + ni * 16 + (lane & 15);
        bfr[ni] = Bs8[nB * 8 + ((kk * 4 + hi) ^ (nB & 7))];
      }
#pragma unroll
      for (int mi = 0; mi < 4; ++mi)
#pragma unroll
        for (int ni = 0; ni < 4; ++ni)
          acc[mi][ni] = __builtin_amdgcn_mfma_f32_16x16x32_bf16(af[mi], bfr[ni], acc[mi][ni], 0, 0, 0);
    }
  }

  // epilogue: x = acc + ph[b,u]; t = tanh(x); partial logit = sum_u t*Wv[u]
  const float* phr = ph + (size_t)b * U_;
  float phv[4], wvv[4];
#pragma unroll
  for (int ni = 0; ni < 4; ++ni) {
    int u = n0 + wc * 64 + ni * 16 + (lane & 15);
    phv[ni] = phr[u];
    wvv[ni] = Wv[u];
  }
#pragma unroll
  for (int mi = 0; mi < 4; ++mi) {
    float cs[4] = {0.f, 0.f, 0.f, 0.f};
#pragma unroll
    for (int ni = 0; ni < 4; ++ni) {
#pragma unroll
      for (int r = 0; r < 4; ++r) {
        float x = acc[mi][ni][r] + phv[ni];
        cs[r] += fast_tanh(x) * wvv[ni];
      }
    }
    // reduce across the 16 column-lanes (C layout: col = lane&15, row = (lane>>4)*4+r)
#pragma unroll
    for (int off = 1; off < 16; off <<= 1) {
#pragma unroll
      for (int r = 0; r < 4; ++r) cs[r] += __shfl_xor(cs[r], off);
    }
    if ((lane & 15) == 0) {
      int g = m0 + wr * 64 + mi * 16 + ((lane >> 4) << 2);
#pragma unroll
      for (int r = 0; r < 4; ++r) atomicAdd(&logits[g + r], cs[r]);
    }
  }
}

// ---------------- fused: softmax over L, then context[b,d] = sum_l w*F ----------------
__global__ void k_smctx(const float* __restrict__ logits, const float* __restrict__ F,
                        float* __restrict__ outw, float* __restrict__ ctx) {
  __shared__ float wl[L_];
  __shared__ f32x4 part[256];
  __shared__ float red[8];
  int b = blockIdx.x, t = threadIdx.x;
  float x = logits[(size_t)b * L_ + t];
  float m = x;
#pragma unroll
  for (int off = 32; off >= 1; off >>= 1) m = fmaxf(m, __shfl_xor(m, off));
  if ((t & 63) == 0) red[t >> 6] = m;
  __syncthreads();
  m = fmaxf(fmaxf(red[0], red[1]), fmaxf(red[2], red[3]));
  float e = __expf(x - m);
  float s = e;
#pragma unroll
  for (int off = 32; off >= 1; off >>= 1) s += __shfl_xor(s, off);
  if ((t & 63) == 0) red[4 + (t >> 6)] = s;
  __syncthreads();
  s = (red[4] + red[5]) + (red[6] + red[7]);
  float w = e / s;
  outw[(size_t)b * L_ + t] = w;
  wl[t] = w;
  __syncthreads();

  int lq = t >> 6, dq = t & 63;
  const f32x4* F4 = (const f32x4*)(F + (size_t)b * L_ * D_);
  f32x4 acc = {0.f, 0.f, 0.f, 0.f};
  for (int l = lq; l < L_; l += 4) acc += wl[l] * F4[l * 64 + dq];
  part[t] = acc;
  __syncthreads();
  if (lq == 0) {
    f32x4 r = (part[t] + part[t + 64]) + (part[t + 128] + part[t + 192]);
    ((f32x4*)ctx)[(size_t)b * 64 + dq] = r;
  }
}

extern "C" void kernel_launch(void* const* d_in, const int* in_sizes, int n_in,
                              void* d_out, int out_size, void* d_ws, size_t ws_size,
                              hipStream_t stream) {
  const float* F      = (const float*)d_in[0];  // [B,L,D]
  const float* hidden = (const float*)d_in[1];  // [B,H]
  const float* W1     = (const float*)d_in[2];  // [D,U]
  const float* b1     = (const float*)d_in[3];  // [U]
  const float* W2     = (const float*)d_in[4];  // [H,U]
  const float* b2     = (const float*)d_in[5];  // [U]
  const float* Wv     = (const float*)d_in[6];  // [U,1]
  // d_in[7] = bv: shift-invariant under softmax, unused

  float* out_ctx = (float*)d_out;                        // [B,D] = 262144 floats
  float* out_w   = out_ctx + (size_t)B_ * D_;            // [B,L,1] = 262144 floats

  char* ws = (char*)d_ws;
  short* W1T   = (short*)ws;                             // 256 KB bf16 [U,D]
  float* ph    = (float*)(ws + 262144);                  // 2 MB fp32 [B,U]
  float* logits = (float*)(ws + 262144 + 2097152);       // 1 MB fp32 [B*L]

  hipMemsetAsync(logits, 0, (size_t)M_ * sizeof(float), stream);
  k_w1t<<<512, 256, 0, stream>>>(W1, W1T);
  k_projh<<<dim3(2, 128), 256, 0, stream>>>(hidden, W2, b1, b2, ph);
  k_gemm<<<8192, 256, 0, stream>>>(F, W1T, ph, Wv, logits);
  k_smctx<<<1024, 256, 0, stream>>>(logits, F, out_w, out_ctx);
}

// Round 7
// 236.550 us; speedup vs baseline: 1.2797x; 1.0168x over previous
//
#include <hip/hip_runtime.h>
#include <hip/hip_bf16.h>

#define B_ 1024
#define L_ 256
#define D_ 256
#define H_ 512
#define U_ 512
#define M_ (B_ * L_)   // 262144 rows of the big GEMM

#define BM 128
#define BN 128
#define BK 64

typedef float f32x4 __attribute__((ext_vector_type(4)));
typedef short bf16x8 __attribute__((ext_vector_type(8)));  // 8 bf16 in 4 VGPRs

__device__ __forceinline__ short f2bf(float f) {
  // round-to-nearest-even fp32 -> bf16 (inputs are finite, no NaN handling)
  unsigned u = __float_as_uint(f);
  u += 0x7fffu + ((u >> 16) & 1u);
  return (short)(u >> 16);
}

__device__ __forceinline__ void load16_g2l(const void* g, void* l) {
  // async global->LDS, 16B per lane; LDS dest must be uniform-base + lane*16
  __builtin_amdgcn_global_load_lds(
      (const __attribute__((address_space(1))) unsigned int*)g,
      (__attribute__((address_space(3))) unsigned int*)l, 16, 0, 0);
}

__device__ __forceinline__ float fast_tanh(float x) {
  float e = __expf(2.0f * x);               // v_exp_f32 based, ~1ulp
  return 1.0f - 2.0f * __builtin_amdgcn_rcpf(e + 1.0f);
}

// ---------------- prep: W1 [D,U] fp32 -> W1T [U,D] bf16 ----------------
__global__ void k_w1t(const float* __restrict__ W1, short* __restrict__ W1T) {
  int idx = blockIdx.x * 256 + threadIdx.x;   // over U_*D_ = 131072
  int u = idx >> 8;      // / D_
  int d = idx & 255;
  W1T[idx] = f2bf(W1[(size_t)d * U_ + u]);
}

// ---------------- projh[b,u] = hidden[b,:] @ W2[:,u] + b1[u] + b2[u] ----------------
__global__ void k_projh(const float* __restrict__ hidden, const float* __restrict__ W2,
                        const float* __restrict__ b1, const float* __restrict__ b2,
                        float* __restrict__ ph) {
  int u = blockIdx.x * 256 + threadIdx.x;
  int b0 = blockIdx.y * 8;
  float acc[8] = {0.f, 0.f, 0.f, 0.f, 0.f, 0.f, 0.f, 0.f};
  for (int h = 0; h < H_; ++h) {
    float w = W2[(size_t)h * U_ + u];
#pragma unroll
    for (int i = 0; i < 8; ++i) acc[i] = fmaf(hidden[(size_t)(b0 + i) * H_ + h], w, acc[i]);
  }
  float bias = b1[u] + b2[u];
#pragma unroll
  for (int i = 0; i < 8; ++i) ph[(size_t)(b0 + i) * U_ + u] = acc[i] + bias;
}

// ---------------- main: logits partials via bf16 MFMA + tanh + Wv reduce ----------------
// grid 8192, XCD-chunked swizzle. 256 threads = 4 waves (2x2 of 64x64).
// Pipelined: next-kt A (regs) and B (g2l -> other LDS half) issued DURING current compute.
__global__ __launch_bounds__(256, 3) void k_gemm(
    const float* __restrict__ F,    // [M_, D_] fp32 features
    const short* __restrict__ W1T,  // [U_, D_] bf16
    const float* __restrict__ ph,   // [B_, U_]
    const float* __restrict__ Wv,   // [U_]
    float* __restrict__ logits) {   // [M_], pre-zeroed
  __shared__ __align__(16) short As[BM * BK];       // 16 KB bf16, swizzled 16B slots
  __shared__ __align__(16) short Bs[2][BN * BK];    // 2 x 16 KB bf16, swizzled (double-buffer)

  const int tid = threadIdx.x;
  const int lane = tid & 63;
  const int hi = lane >> 4;
  const int wid = tid >> 6;
  const int wr = wid >> 1, wc = wid & 1;
  // XCD swizzle: XCD = blockIdx%8 owns a contiguous tile chunk -> the 4 ntile
  // blocks sharing an A-tile run on the SAME XCD's L2.
  const int tile = ((blockIdx.x & 7) << 10) | (blockIdx.x >> 3);
  const int ntile = tile & 3;
  const int mtile = tile >> 2;
  const int m0 = mtile * BM;
  const int n0 = ntile * BN;
  const int b = m0 >> 8;   // 128-row tile lies within one batch (128 | 256)

  const bf16x8* As8 = (const bf16x8*)As;

  // ---- staging addresses (row/kq fixed per thread, advance by BK per kt) ----
  // 1024 slots (128 rows x 8 slots of 8 bf16). slot s holds global chunk kq = (s&7)^(row&7).
  const float* agp[4];
  int aslot[4];
  const short* bgp[4];
#pragma unroll
  for (int i = 0; i < 4; ++i) {
    int s = i * 256 + tid;
    int arow = s >> 3;
    int akq = (s & 7) ^ (arow & 7);
    agp[i] = F + (size_t)(m0 + arow) * D_ + akq * 8;
    aslot[i] = s;
    bgp[i] = W1T + (size_t)(n0 + arow) * D_ + akq * 8;  // same (row,slot) decomposition
  }

  f32x4 acc[4][4];
  const f32x4 fz = {0.f, 0.f, 0.f, 0.f};
#pragma unroll
  for (int mi = 0; mi < 4; ++mi)
#pragma unroll
    for (int ni = 0; ni < 4; ++ni) acc[mi][ni] = fz;

  // ---- prologue: issue kt=0 loads (one exposed HBM latency, once) ----
  f32x4 ar[4][2];
#pragma unroll
  for (int i = 0; i < 4; ++i) {
    ar[i][0] = *(const f32x4*)(agp[i]);
    ar[i][1] = *(const f32x4*)(agp[i] + 4);
    agp[i] += BK;
  }
#pragma unroll
  for (int i = 0; i < 4; ++i) {
    load16_g2l(bgp[i], &Bs[0][(size_t)(i * 256 + tid) * 8]);
    bgp[i] += BK;
  }

  for (int kt = 0; kt < 4; ++kt) {
    const bf16x8* BsC = (const bf16x8*)Bs[kt & 1];
    __syncthreads();     // WAR: waves done reading As(kt-1); drains in-flight A/B (landed during prior compute)
    // A: cast once, vector LDS write (slot = linear s; source was pre-swizzled)
#pragma unroll
    for (int i = 0; i < 4; ++i) {
      bf16x8 w;
#pragma unroll
      for (int j = 0; j < 4; ++j) { w[j] = f2bf(ar[i][0][j]); w[4 + j] = f2bf(ar[i][1][j]); }
      ((bf16x8*)As)[aslot[i]] = w;
    }
    __syncthreads();     // RAW: As(kt) visible to all waves
    if (kt < 3) {
      // prefetch kt+1 DURING compute: A -> regs (same set, already consumed), B -> other LDS half
#pragma unroll
      for (int i = 0; i < 4; ++i) {
        ar[i][0] = *(const f32x4*)(agp[i]);
        ar[i][1] = *(const f32x4*)(agp[i] + 4);
        agp[i] += BK;
      }
#pragma unroll
      for (int i = 0; i < 4; ++i) {
        load16_g2l(bgp[i], &Bs[(kt + 1) & 1][(size_t)(i * 256 + tid) * 8]);
        bgp[i] += BK;
      }
    }

#pragma unroll
    for (int kk = 0; kk < 2; ++kk) {
      bf16x8 af[4], bfr[4];
#pragma unroll
      for (int mi = 0; mi < 4; ++mi) {
        int rA = wr * 64 + mi * 16 + (lane & 15);
        af[mi] = As8[rA * 8 + ((kk * 4 + hi) ^ (rA & 7))];
      }
#pragma unroll
      for (int ni = 0; ni < 4; ++ni) {
        int nB = wc * 64 + ni * 16 + (lane & 15);
        bfr[ni] = BsC[nB * 8 + ((kk * 4 + hi) ^ (nB & 7))];
      }
#pragma unroll
      for (int mi = 0; mi < 4; ++mi)
#pragma unroll
        for (int ni = 0; ni < 4; ++ni)
          acc[mi][ni] = __builtin_amdgcn_mfma_f32_16x16x32_bf16(af[mi], bfr[ni], acc[mi][ni], 0, 0, 0);
    }
  }

  // epilogue: x = acc + ph[b,u]; t = tanh(x); partial logit = sum_u t*Wv[u]
  const float* phr = ph + (size_t)b * U_;
  float phv[4], wvv[4];
#pragma unroll
  for (int ni = 0; ni < 4; ++ni) {
    int u = n0 + wc * 64 + ni * 16 + (lane & 15);
    phv[ni] = phr[u];
    wvv[ni] = Wv[u];
  }
#pragma unroll
  for (int mi = 0; mi < 4; ++mi) {
    float cs[4] = {0.f, 0.f, 0.f, 0.f};
#pragma unroll
    for (int ni = 0; ni < 4; ++ni) {
#pragma unroll
      for (int r = 0; r < 4; ++r) {
        float x = acc[mi][ni][r] + phv[ni];
        cs[r] += fast_tanh(x) * wvv[ni];
      }
    }
    // reduce across the 16 column-lanes (C layout: col = lane&15, row = (lane>>4)*4+r)
#pragma unroll
    for (int off = 1; off < 16; off <<= 1) {
#pragma unroll
      for (int r = 0; r < 4; ++r) cs[r] += __shfl_xor(cs[r], off);
    }
    if ((lane & 15) == 0) {
      int g = m0 + wr * 64 + mi * 16 + ((lane >> 4) << 2);
#pragma unroll
      for (int r = 0; r < 4; ++r) atomicAdd(&logits[g + r], cs[r]);
    }
  }
}

// ---------------- fused: softmax over L, then context[b,d] = sum_l w*F ----------------
__global__ void k_smctx(const float* __restrict__ logits, const float* __restrict__ F,
                        float* __restrict__ outw, float* __restrict__ ctx) {
  __shared__ float wl[L_];
  __shared__ f32x4 part[256];
  __shared__ float red[8];
  int b = blockIdx.x, t = threadIdx.x;
  float x = logits[(size_t)b * L_ + t];
  float m = x;
#pragma unroll
  for (int off = 32; off >= 1; off >>= 1) m = fmaxf(m, __shfl_xor(m, off));
  if ((t & 63) == 0) red[t >> 6] = m;
  __syncthreads();
  m = fmaxf(fmaxf(red[0], red[1]), fmaxf(red[2], red[3]));
  float e = __expf(x - m);
  float s = e;
#pragma unroll
  for (int off = 32; off >= 1; off >>= 1) s += __shfl_xor(s, off);
  if ((t & 63) == 0) red[4 + (t >> 6)] = s;
  __syncthreads();
  s = (red[4] + red[5]) + (red[6] + red[7]);
  float w = e / s;
  outw[(size_t)b * L_ + t] = w;
  wl[t] = w;
  __syncthreads();

  int lq = t >> 6, dq = t & 63;
  const f32x4* F4 = (const f32x4*)(F + (size_t)b * L_ * D_);
  f32x4 acc = {0.f, 0.f, 0.f, 0.f};
  for (int l = lq; l < L_; l += 4) acc += wl[l] * F4[l * 64 + dq];
  part[t] = acc;
  __syncthreads();
  if (lq == 0) {
    f32x4 r = (part[t] + part[t + 64]) + (part[t + 128] + part[t + 192]);
    ((f32x4*)ctx)[(size_t)b * 64 + dq] = r;
  }
}

extern "C" void kernel_launch(void* const* d_in, const int* in_sizes, int n_in,
                              void* d_out, int out_size, void* d_ws, size_t ws_size,
                              hipStream_t stream) {
  const float* F      = (const float*)d_in[0];  // [B,L,D]
  const float* hidden = (const float*)d_in[1];  // [B,H]
  const float* W1     = (const float*)d_in[2];  // [D,U]
  const float* b1     = (const float*)d_in[3];  // [U]
  const float* W2     = (const float*)d_in[4];  // [H,U]
  const float* b2     = (const float*)d_in[5];  // [U]
  const float* Wv     = (const float*)d_in[6];  // [U,1]
  // d_in[7] = bv: shift-invariant under softmax, unused

  float* out_ctx = (float*)d_out;                        // [B,D] = 262144 floats
  float* out_w   = out_ctx + (size_t)B_ * D_;            // [B,L,1] = 262144 floats

  char* ws = (char*)d_ws;
  short* W1T   = (short*)ws;                             // 256 KB bf16 [U,D]
  float* ph    = (float*)(ws + 262144);                  // 2 MB fp32 [B,U]
  float* logits = (float*)(ws + 262144 + 2097152);       // 1 MB fp32 [B*L]

  hipMemsetAsync(logits, 0, (size_t)M_ * sizeof(float), stream);
  k_w1t<<<512, 256, 0, stream>>>(W1, W1T);
  k_projh<<<dim3(2, 128), 256, 0, stream>>>(hidden, W2, b1, b2, ph);
  k_gemm<<<8192, 256, 0, stream>>>(F, W1T, ph, Wv, logits);
  k_smctx<<<1024, 256, 0, stream>>>(logits, F, out_w, out_ctx);
}